// Round 6
// baseline (340.274 us; speedup 1.0000x reference)
//
#include <hip/hip_runtime.h>

#define FEAT 128
#define BN_EPS 1e-5f
#define P_CNT 1024            // edge-chunk blocks for count/scatter
#define BKT_SHIFT 9           // 512 nodes per coarse bucket
#define BKT_NODES 512

typedef __attribute__((ext_vector_type(8))) short s8frag;
typedef __attribute__((ext_vector_type(4))) float f4frag;

union FragU { uint4 u; s8frag v; };

__device__ __forceinline__ unsigned short f2bf(float f) {
    unsigned u = __float_as_uint(f);
    unsigned r = (u + 0x7fffu + ((u >> 16) & 1u)) >> 16;
    return (unsigned short)r;
}
__device__ __forceinline__ void unpack2(unsigned d, float& lo, float& hi) {
    lo = __uint_as_float(d << 16);
    hi = __uint_as_float(d & 0xffff0000u);
}
__device__ __forceinline__ void acc8(float* acc, uint4 d) {
    float l, h;
    unpack2(d.x, l, h); acc[0] += l; acc[1] += h;
    unpack2(d.y, l, h); acc[2] += l; acc[3] += h;
    unpack2(d.z, l, h); acc[4] += l; acc[5] += h;
    unpack2(d.w, l, h); acc[6] += l; acc[7] += h;
}

// ---------------- FRONT: LDS-histogram count (A) | x->bf16 (B) | weight prep (C)
__global__ __launch_bounds__(256) void front2(
    const int* __restrict__ dst, int E, int per, int NB,
    unsigned* __restrict__ histT,               // [NB][P_CNT] transposed hist
    const float* __restrict__ x, unsigned short* __restrict__ xb, int XB,
    const float* __restrict__ W1l, const float* __restrict__ W1r,
    const float* __restrict__ W2l, const float* __restrict__ W2r,
    const float* __restrict__ b1, const float* __restrict__ g,
    const float* __restrict__ bt, const float* __restrict__ mu,
    const float* __restrict__ var, const float* __restrict__ b2,
    unsigned short* __restrict__ Wb1, unsigned short* __restrict__ Wb2,
    float* __restrict__ bnsc, float* __restrict__ bnsh, float* __restrict__ cb2)
{
    const int bid = blockIdx.x;
    const int tid = threadIdx.x;
    if (bid < P_CNT) {
        // ---- count: LDS histogram of dst>>9 over this block's edge chunk ----
        __shared__ unsigned h[256];
        for (int i = tid; i < NB; i += 256) h[i] = 0u;
        __syncthreads();
        int s = bid * per;
        int e1 = min(E, s + per);
        for (int e = s + tid; e < e1; e += 256)
            atomicAdd(&h[((unsigned)dst[e]) >> BKT_SHIFT], 1u);
        __syncthreads();
        for (int i = tid; i < NB; i += 256)
            histT[(size_t)i * P_CNT + bid] = h[i];
    } else if (bid < P_CNT + XB) {
        // ---- convert x -> bf16 (8 elems/thread) ----
        int t = (bid - P_CNT) * 256 + tid;
        const float4* src = (const float4*)(x) + (size_t)t * 2;
        float4 a = src[0], b = src[1];
        uint4 o;
        o.x = f2bf(a.x) | ((unsigned)f2bf(a.y) << 16);
        o.y = f2bf(a.z) | ((unsigned)f2bf(a.w) << 16);
        o.z = f2bf(b.x) | ((unsigned)f2bf(b.y) << 16);
        o.w = f2bf(b.z) | ((unsigned)f2bf(b.w) << 16);
        ((uint4*)xb)[t] = o;
    } else {
        // ---- weight prep + BN constants ----
        int idx = (bid - P_CNT - XB) * 256 + tid;
        if (idx < 128 * 256) {
            int n = idx >> 8, k = idx & 255;
            float w = (k < 128) ? W1l[n * 128 + k] : W1r[n * 128 + (k - 128)];
            Wb1[idx] = f2bf(w);
        }
        if (idx < 128 * 128) {
            int n = idx >> 7, k = idx & 127;
            float w = (n < 64) ? W2l[n * 128 + k] : W2r[(n - 64) * 128 + k];
            Wb2[idx] = f2bf(w);
        }
        if (idx < 128) {
            float sc = rsqrtf(var[idx] + BN_EPS) * g[idx];
            bnsc[idx] = sc;
            bnsh[idx] = sc * (b1[idx] - mu[idx]) + bt[idx];
            cb2[idx] = (idx < 64) ? 0.f : b2[idx - 64];
        }
    }
}

// ---------------- per-block exclusive scan, stride-1 input ------------------
__global__ void scan_block_c(const unsigned* __restrict__ in, unsigned* __restrict__ excl,
                             unsigned* __restrict__ partials, int M) {
    __shared__ unsigned buf[256];
    int i = blockIdx.x * 256 + threadIdx.x;
    unsigned v = (i < M) ? in[i] : 0u;
    buf[threadIdx.x] = v;
    __syncthreads();
    for (int off = 1; off < 256; off <<= 1) {
        unsigned t = (threadIdx.x >= (unsigned)off) ? buf[threadIdx.x - off] : 0u;
        __syncthreads();
        buf[threadIdx.x] += t;
        __syncthreads();
    }
    if (i < M) excl[i] = buf[threadIdx.x] - v;
    if (threadIdx.x == 255) partials[blockIdx.x] = buf[255];
}

// ---------------- finish: each block reduces partials[0..b-1] itself ---------
__global__ void scan_finish(unsigned* __restrict__ arr,
                            const unsigned* __restrict__ partials, int M, int E) {
    __shared__ unsigned red[256];
    int b = blockIdx.x;
    unsigned s = 0;
    for (int t = threadIdx.x; t < b; t += 256) s += partials[t];
    red[threadIdx.x] = s;
    __syncthreads();
    for (int off = 128; off > 0; off >>= 1) {
        if ((int)threadIdx.x < off) red[threadIdx.x] += red[threadIdx.x + off];
        __syncthreads();
    }
    unsigned base = red[0];
    int i = b * 256 + threadIdx.x;
    if (i < M) arr[i] += base;
    if (i == 0) arr[M] = (unsigned)E;   // uniform bucket-end for the last bucket
}

// ---------------- scatter edges into coarse buckets (LDS offsets) ------------
__global__ __launch_bounds__(256) void scatter_bucket(
    const int* __restrict__ src, const int* __restrict__ dst, int E, int per, int NB,
    const unsigned* __restrict__ hexcl, unsigned* __restrict__ buck)
{
    __shared__ unsigned cnt[256];
    const int p = blockIdx.x, tid = threadIdx.x;
    for (int i = tid; i < NB; i += 256) cnt[i] = hexcl[(size_t)i * P_CNT + p];
    __syncthreads();
    int s = p * per, e1 = min(E, s + per);
    for (int e = s + tid; e < e1; e += 256) {
        unsigned d = (unsigned)dst[e];
        unsigned pos = atomicAdd(&cnt[d >> BKT_SHIFT], 1u);
        buck[pos] = ((unsigned)src[e] << BKT_SHIFT) | (d & (BKT_NODES - 1u));
    }
}

// ---------------- per-bucket CSR: 512-node LDS hist + scan -> row_start/csr --
// (r5's src-band LDS-staged variant was NULL for fetch and +6us here; reverted)
__global__ __launch_bounds__(512) void bucket_csr(
    const unsigned* __restrict__ buck, const unsigned* __restrict__ hexcl,
    unsigned* __restrict__ row_start, unsigned* __restrict__ csr_src, int N, int E)
{
    __shared__ unsigned h[BKT_NODES];
    __shared__ unsigned sc[BKT_NODES];
    const int b = blockIdx.x, tid = threadIdx.x;
    const unsigned bs = hexcl[(size_t)b * P_CNT];
    const unsigned be = hexcl[(size_t)(b + 1) * P_CNT];
    h[tid] = 0u;
    __syncthreads();
    for (unsigned e = bs + tid; e < be; e += BKT_NODES)
        atomicAdd(&h[buck[e] & (BKT_NODES - 1u)], 1u);
    __syncthreads();
    unsigned v = h[tid];
    sc[tid] = v;
    __syncthreads();
    for (int off = 1; off < BKT_NODES; off <<= 1) {
        unsigned t = (tid >= off) ? sc[tid - off] : 0u;
        __syncthreads();
        sc[tid] += t;
        __syncthreads();
    }
    unsigned pos0 = bs + sc[tid] - v;   // global CSR start for this node
    int node = b * BKT_NODES + tid;
    if (node < N) row_start[node] = pos0;
    h[tid] = pos0;                      // reuse as running position counters
    __syncthreads();
    for (unsigned e = bs + tid; e < be; e += BKT_NODES) {
        unsigned pk = buck[e];
        unsigned pos = atomicAdd(&h[pk & (BKT_NODES - 1u)], 1u);
        csr_src[pos] = pk >> BKT_SHIFT;
    }
    if (b == 0 && tid == 0) row_start[N] = (unsigned)E;
}

// ---------------- gather + mean, XCD-split by 128B feature half --------------
// Each 256B xb row = 2 cache LINES (feats 0-63 / 64-127). With round-robin
// dispatch (xcd = bid&7), half = (bid>>2)&1 pins XCDs 0-3 to half 0 and
// XCDs 4-7 to half 1 -> each XCD's L2 only touches HALF of xb's lines.
// (Splitting below 128B line granularity REGRESSES: r4 measured 2.1x fetch.)
// 8 lanes/node-half, 32 node-jobs/block, unroll 8.
__global__ __launch_bounds__(256) void gather_mean_bf(const unsigned short* __restrict__ xb,
                                                      const unsigned* __restrict__ row_start,
                                                      const unsigned* __restrict__ csr_src,
                                                      unsigned short* __restrict__ aggb,
                                                      int N, int NBLK) {
    const int bid = blockIdx.x;
    const int half = (bid >> 2) & 1;                  // constant per XCD group
    const int nodeblk = (bid & 3) | ((bid >> 3) << 2);
    if (nodeblk >= NBLK) return;
    const int node = nodeblk * 32 + (threadIdx.x >> 3);
    if (node >= N) return;
    const int f = half * 64 + (threadIdx.x & 7) * 8;
    unsigned s0 = row_start[node], s1 = row_start[node + 1];
    float acc[8];
#pragma unroll
    for (int i = 0; i < 8; i++) acc[i] = 0.f;
    unsigned i = s0;
    for (; i + 8 <= s1; i += 8) {
        unsigned i0 = csr_src[i + 0], i1 = csr_src[i + 1];
        unsigned i2 = csr_src[i + 2], i3 = csr_src[i + 3];
        unsigned i4 = csr_src[i + 4], i5 = csr_src[i + 5];
        unsigned i6 = csr_src[i + 6], i7 = csr_src[i + 7];
        uint4 d0 = *(const uint4*)(xb + (size_t)i0 * 128 + f);
        uint4 d1 = *(const uint4*)(xb + (size_t)i1 * 128 + f);
        uint4 d2 = *(const uint4*)(xb + (size_t)i2 * 128 + f);
        uint4 d3 = *(const uint4*)(xb + (size_t)i3 * 128 + f);
        uint4 d4 = *(const uint4*)(xb + (size_t)i4 * 128 + f);
        uint4 d5 = *(const uint4*)(xb + (size_t)i5 * 128 + f);
        uint4 d6 = *(const uint4*)(xb + (size_t)i6 * 128 + f);
        uint4 d7 = *(const uint4*)(xb + (size_t)i7 * 128 + f);
        acc8(acc, d0); acc8(acc, d1); acc8(acc, d2); acc8(acc, d3);
        acc8(acc, d4); acc8(acc, d5); acc8(acc, d6); acc8(acc, d7);
    }
    if (i + 4 <= s1) {
        unsigned i0 = csr_src[i + 0], i1 = csr_src[i + 1];
        unsigned i2 = csr_src[i + 2], i3 = csr_src[i + 3];
        uint4 d0 = *(const uint4*)(xb + (size_t)i0 * 128 + f);
        uint4 d1 = *(const uint4*)(xb + (size_t)i1 * 128 + f);
        uint4 d2 = *(const uint4*)(xb + (size_t)i2 * 128 + f);
        uint4 d3 = *(const uint4*)(xb + (size_t)i3 * 128 + f);
        acc8(acc, d0); acc8(acc, d1); acc8(acc, d2); acc8(acc, d3);
        i += 4;
    }
    if (i + 2 <= s1) {
        unsigned i0 = csr_src[i + 0], i1 = csr_src[i + 1];
        uint4 d0 = *(const uint4*)(xb + (size_t)i0 * 128 + f);
        uint4 d1 = *(const uint4*)(xb + (size_t)i1 * 128 + f);
        acc8(acc, d0); acc8(acc, d1);
        i += 2;
    }
    if (i < s1) {
        unsigned i0 = csr_src[i];
        uint4 d0 = *(const uint4*)(xb + (size_t)i0 * 128 + f);
        acc8(acc, d0);
    }
    float inv = (s1 > s0) ? 1.0f / (float)(s1 - s0) : 0.f;
    uint4 o;
    o.x = f2bf(acc[0] * inv) | ((unsigned)f2bf(acc[1] * inv) << 16);
    o.y = f2bf(acc[2] * inv) | ((unsigned)f2bf(acc[3] * inv) << 16);
    o.z = f2bf(acc[4] * inv) | ((unsigned)f2bf(acc[5] * inv) << 16);
    o.w = f2bf(acc[6] * inv) | ((unsigned)f2bf(acc[7] * inv) << 16);
    *(uint4*)(aggb + (size_t)node * 128 + f) = o;
}

// ---------------- dense: layer1 GEMM+BN/ReLU + layer2 GEMM -------------------
// Weights read DIRECTLY from global (96KB total, L1/L2-resident, identical
// lines across all blocks) -> no weight LDS staging, 1 barrier instead of 7,
// LDS 48KB -> 16KB (As transpose only) -> occupancy 3 -> ~5 blocks/CU.
// Fragment contents are byte-identical to the old swizzled-LDS path.
__global__ __launch_bounds__(256) void sage_dense(
    const unsigned short* __restrict__ aggb,
    const unsigned short* __restrict__ xb,
    const unsigned short* __restrict__ Wb1,   // [128][256]
    const unsigned short* __restrict__ Wb2,   // [128][128]
    const float* __restrict__ bnsc, const float* __restrict__ bnsh,
    const float* __restrict__ cb2,
    unsigned short* __restrict__ uvb, int N)
{
    __shared__ __align__(16) unsigned short As[64 * 128];   // 16 KB (h transpose)
    uint4* AsV = (uint4*)As;

    const int tid = threadIdx.x;
    const int wave = tid >> 6;
    const int lane = tid & 63;
    const int mr = lane & 15;
    const int q = lane >> 4;
    const int m0 = blockIdx.x * 64;
    const int mw = m0 + wave * 16 + mr;
    const bool mv = mw < N;

    FragU ag[4], ax[4];
#pragma unroll
    for (int kc4 = 0; kc4 < 4; kc4++) {
        ag[kc4].u = make_uint4(0u, 0u, 0u, 0u);
        ax[kc4].u = make_uint4(0u, 0u, 0u, 0u);
        if (mv) {
            ag[kc4].u = *(const uint4*)(aggb + (size_t)mw * 128 + kc4 * 32 + q * 8);
            ax[kc4].u = *(const uint4*)(xb + (size_t)mw * 128 + kc4 * 32 + q * 8);
        }
    }

    f4frag acc[8];
#pragma unroll
    for (int j = 0; j < 8; j++)
#pragma unroll
        for (int r = 0; r < 4; r++) acc[j][r] = 0.f;

    // layer-1 first K-half: agg @ W1l^T   (Wb1 cols 0..127)
#pragma unroll
    for (int kc4 = 0; kc4 < 4; kc4++) {
#pragma unroll
        for (int j = 0; j < 8; j++) {
            FragU b;
            b.u = *(const uint4*)(Wb1 + (size_t)(j * 16 + mr) * 256 + kc4 * 32 + q * 8);
            acc[j] = __builtin_amdgcn_mfma_f32_16x16x32_bf16(ag[kc4].v, b.v, acc[j], 0, 0, 0);
        }
    }
    // layer-1 second K-half: x @ W1r^T    (Wb1 cols 128..255)
#pragma unroll
    for (int kc4 = 0; kc4 < 4; kc4++) {
#pragma unroll
        for (int j = 0; j < 8; j++) {
            FragU b;
            b.u = *(const uint4*)(Wb1 + (size_t)(j * 16 + mr) * 256 + 128 + kc4 * 32 + q * 8);
            acc[j] = __builtin_amdgcn_mfma_f32_16x16x32_bf16(ax[kc4].v, b.v, acc[j], 0, 0, 0);
        }
    }

    // BN + ReLU -> As (h transposed, XOR-swizzled)
#pragma unroll
    for (int j = 0; j < 8; j++) {
        int n = j * 16 + mr;
        float sc = bnsc[n], sh = bnsh[n];
        int cn = n >> 3;
#pragma unroll
        for (int r = 0; r < 4; r++) {
            int ml = wave * 16 + q * 4 + r;
            float v = fmaxf(acc[j][r] * sc + sh, 0.f);
            As[(ml * 16 + (cn ^ (ml & 15))) * 8 + (n & 7)] = f2bf(v);
        }
    }
    __syncthreads();

    // layer-2: h @ [W2l|W2r]^T
#pragma unroll
    for (int j = 0; j < 8; j++)
#pragma unroll
        for (int r = 0; r < 4; r++) acc[j][r] = 0.f;
    const int arow = (wave * 16 + mr) * 16;
#pragma unroll
    for (int kc4 = 0; kc4 < 4; kc4++) {
        FragU a;
        a.u = AsV[arow + ((kc4 * 4 + q) ^ mr)];
#pragma unroll
        for (int j = 0; j < 8; j++) {
            FragU b;
            b.u = *(const uint4*)(Wb2 + (size_t)(j * 16 + mr) * 128 + kc4 * 32 + q * 8);
            acc[j] = __builtin_amdgcn_mfma_f32_16x16x32_bf16(a.v, b.v, acc[j], 0, 0, 0);
        }
    }

#pragma unroll
    for (int j = 0; j < 8; j++) {
        int n = j * 16 + mr;
        float cb = cb2[n];
#pragma unroll
        for (int r = 0; r < 4; r++) {
            int mrow = m0 + wave * 16 + q * 4 + r;
            if (mrow < N)
                uvb[(size_t)mrow * 128 + n] = f2bf(acc[j][r] + cb);
        }
    }
}

// ---------------- layer-2 finish: out = mean_agg(u) + v, fp32, unroll 8 ------
__global__ __launch_bounds__(256) void gather_out_bf(const unsigned short* __restrict__ uvb,
                                                     const unsigned* __restrict__ row_start,
                                                     const unsigned* __restrict__ csr_src,
                                                     float* __restrict__ out, int N) {
    int gid = blockIdx.x * 256 + threadIdx.x;
    int node = gid >> 3;
    if (node >= N) return;
    int f = (threadIdx.x & 7) * 8;
    unsigned s0 = row_start[node], s1 = row_start[node + 1];
    float acc[8];
#pragma unroll
    for (int i = 0; i < 8; i++) acc[i] = 0.f;
    unsigned i = s0;
    for (; i + 8 <= s1; i += 8) {
        unsigned i0 = csr_src[i + 0], i1 = csr_src[i + 1];
        unsigned i2 = csr_src[i + 2], i3 = csr_src[i + 3];
        unsigned i4 = csr_src[i + 4], i5 = csr_src[i + 5];
        unsigned i6 = csr_src[i + 6], i7 = csr_src[i + 7];
        uint4 d0 = *(const uint4*)(uvb + (size_t)i0 * 128 + f);
        uint4 d1 = *(const uint4*)(uvb + (size_t)i1 * 128 + f);
        uint4 d2 = *(const uint4*)(uvb + (size_t)i2 * 128 + f);
        uint4 d3 = *(const uint4*)(uvb + (size_t)i3 * 128 + f);
        uint4 d4 = *(const uint4*)(uvb + (size_t)i4 * 128 + f);
        uint4 d5 = *(const uint4*)(uvb + (size_t)i5 * 128 + f);
        uint4 d6 = *(const uint4*)(uvb + (size_t)i6 * 128 + f);
        uint4 d7 = *(const uint4*)(uvb + (size_t)i7 * 128 + f);
        acc8(acc, d0); acc8(acc, d1); acc8(acc, d2); acc8(acc, d3);
        acc8(acc, d4); acc8(acc, d5); acc8(acc, d6); acc8(acc, d7);
    }
    if (i + 4 <= s1) {
        unsigned i0 = csr_src[i + 0], i1 = csr_src[i + 1];
        unsigned i2 = csr_src[i + 2], i3 = csr_src[i + 3];
        uint4 d0 = *(const uint4*)(uvb + (size_t)i0 * 128 + f);
        uint4 d1 = *(const uint4*)(uvb + (size_t)i1 * 128 + f);
        uint4 d2 = *(const uint4*)(uvb + (size_t)i2 * 128 + f);
        uint4 d3 = *(const uint4*)(uvb + (size_t)i3 * 128 + f);
        acc8(acc, d0); acc8(acc, d1); acc8(acc, d2); acc8(acc, d3);
        i += 4;
    }
    if (i + 2 <= s1) {
        unsigned i0 = csr_src[i + 0], i1 = csr_src[i + 1];
        uint4 d0 = *(const uint4*)(uvb + (size_t)i0 * 128 + f);
        uint4 d1 = *(const uint4*)(uvb + (size_t)i1 * 128 + f);
        acc8(acc, d0); acc8(acc, d1);
        i += 2;
    }
    if (i < s1) {
        unsigned i0 = csr_src[i];
        uint4 d0 = *(const uint4*)(uvb + (size_t)i0 * 128 + f);
        acc8(acc, d0);
    }
    float inv = (s1 > s0) ? 1.0f / (float)(s1 - s0) : 0.f;
    uint4 dv = *(const uint4*)(uvb + (size_t)node * 128 + 64 + f);
    float vv[8];
    unpack2(dv.x, vv[0], vv[1]);
    unpack2(dv.y, vv[2], vv[3]);
    unpack2(dv.z, vv[4], vv[5]);
    unpack2(dv.w, vv[6], vv[7]);
    float4 o0 = make_float4(acc[0] * inv + vv[0], acc[1] * inv + vv[1],
                            acc[2] * inv + vv[2], acc[3] * inv + vv[3]);
    float4 o1 = make_float4(acc[4] * inv + vv[4], acc[5] * inv + vv[5],
                            acc[6] * inv + vv[6], acc[7] * inv + vv[7]);
    *(float4*)(out + (size_t)node * 64 + f) = o0;
    *(float4*)(out + (size_t)node * 64 + f + 4) = o1;
}

extern "C" void kernel_launch(void* const* d_in, const int* in_sizes, int n_in,
                              void* d_out, int out_size, void* d_ws, size_t ws_size,
                              hipStream_t stream) {
    const float* x     = (const float*)d_in[0];
    const int*   edge  = (const int*)d_in[1];
    const float* W1l   = (const float*)d_in[2];
    const float* b1    = (const float*)d_in[3];
    const float* W1r   = (const float*)d_in[4];
    const float* gamma = (const float*)d_in[5];
    const float* beta  = (const float*)d_in[6];
    const float* mean  = (const float*)d_in[7];
    const float* var   = (const float*)d_in[8];
    const float* W2l   = (const float*)d_in[9];
    const float* b2    = (const float*)d_in[10];
    const float* W2r   = (const float*)d_in[11];

    const int N = in_sizes[0] / FEAT;
    const int E = in_sizes[1] / 2;
    const int* srcI = edge;
    const int* dstI = edge + E;

    const int NB  = (N + BKT_NODES - 1) >> BKT_SHIFT;  // coarse buckets (196)
    const int M   = NB * P_CNT;                        // hist entries (200704)
    const int per = (E + P_CNT - 1) / P_CNT;           // edges per chunk block

    unsigned short* uvb  = (unsigned short*)d_ws;      // N*128
    unsigned short* aggb = uvb + (size_t)N * 128;      // N*128
    unsigned short* xb   = aggb + (size_t)N * 128;     // N*128
    unsigned short* Wb1  = xb + (size_t)N * 128;       // 128*256
    unsigned short* Wb2  = Wb1 + 256 * 128;            // 128*128
    float* bnsc = (float*)(Wb2 + 128 * 128);           // 128
    float* bnsh = bnsc + 128;                          // 128
    float* cb2  = bnsh + 128;                          // 128
    unsigned* histT     = (unsigned*)(cb2 + 128);      // M+1
    unsigned* hexcl     = histT + (M + 1);             // M+1
    unsigned* partials  = hexcl + (M + 1);             // 1024
    unsigned* row_start = partials + 1024;             // N+1
    unsigned* buck      = row_start + (N + 1);         // E (packed src|dstlow)
    unsigned* csr_src   = buck + E;                    // E

    float* outp = (float*)d_out;

    // front: LDS-hist count | convert | prep, one dispatch, no memset needed
    const int total8 = N * FEAT / 8;
    const int XB = (total8 + 255) / 256;
    const int PB = (128 * 256 + 255) / 256;            // weight-prep blocks
    front2<<<P_CNT + XB + PB, 256, 0, stream>>>(
        dstI, E, per, NB, histT, x, xb, XB,
        W1l, W1r, W2l, W2r, b1, gamma, beta, mean, var, b2,
        Wb1, Wb2, bnsc, bnsh, cb2);

    scan_block_c<<<M / 256, 256, 0, stream>>>(histT, hexcl, partials, M);
    scan_finish<<<M / 256, 256, 0, stream>>>(hexcl, partials, M, E);
    scatter_bucket<<<P_CNT, 256, 0, stream>>>(srcI, dstI, E, per, NB, hexcl, buck);
    bucket_csr<<<NB, BKT_NODES, 0, stream>>>(buck, hexcl, row_start, csr_src, N, E);

    // gather_mean: 128B-half XCD split; 32 nodes/block, 2 halves
    {
        const int NBLK = (N + 31) / 32;                 // node-blocks per half
        const int G = 8 * ((2 * NBLK + 7) / 8);         // both halves, xcd-aligned
        gather_mean_bf<<<G, 256, 0, stream>>>(xb, row_start, csr_src, aggb, N, NBLK);
    }
    sage_dense<<<(N + 63) / 64, 256, 0, stream>>>(aggb, xb, Wb1, Wb2, bnsc, bnsh, cb2, uvb, N);
    gather_out_bf<<<(N * 8 + 255) / 256, 256, 0, stream>>>(uvb, row_start, csr_src, outp, N);
}

// Round 7
// 312.196 us; speedup vs baseline: 1.0899x; 1.0899x over previous
//
#include <hip/hip_runtime.h>

#define FEAT 128
#define BN_EPS 1e-5f
#define P_CNT 1024            // edge-chunk blocks for count/scatter
#define BKT_SHIFT 9           // 512 nodes per coarse bucket
#define BKT_NODES 512

typedef __attribute__((ext_vector_type(8))) short s8frag;
typedef __attribute__((ext_vector_type(4))) float f4frag;

union FragU { uint4 u; s8frag v; };

__device__ __forceinline__ unsigned short f2bf(float f) {
    unsigned u = __float_as_uint(f);
    unsigned r = (u + 0x7fffu + ((u >> 16) & 1u)) >> 16;
    return (unsigned short)r;
}
__device__ __forceinline__ void unpack2(unsigned d, float& lo, float& hi) {
    lo = __uint_as_float(d << 16);
    hi = __uint_as_float(d & 0xffff0000u);
}
__device__ __forceinline__ void acc8(float* acc, uint4 d) {
    float l, h;
    unpack2(d.x, l, h); acc[0] += l; acc[1] += h;
    unpack2(d.y, l, h); acc[2] += l; acc[3] += h;
    unpack2(d.z, l, h); acc[4] += l; acc[5] += h;
    unpack2(d.w, l, h); acc[6] += l; acc[7] += h;
}

// ---------------- FRONT: LDS-histogram count (A) | x->bf16 (B) | weight prep (C)
__global__ __launch_bounds__(256) void front2(
    const int* __restrict__ dst, int E, int per, int NB,
    unsigned* __restrict__ histT,               // [NB][P_CNT] transposed hist
    const float* __restrict__ x, unsigned short* __restrict__ xb, int XB,
    const float* __restrict__ W1l, const float* __restrict__ W1r,
    const float* __restrict__ W2l, const float* __restrict__ W2r,
    const float* __restrict__ b1, const float* __restrict__ g,
    const float* __restrict__ bt, const float* __restrict__ mu,
    const float* __restrict__ var, const float* __restrict__ b2,
    unsigned short* __restrict__ Wb1, unsigned short* __restrict__ Wb2,
    float* __restrict__ bnsc, float* __restrict__ bnsh, float* __restrict__ cb2)
{
    const int bid = blockIdx.x;
    const int tid = threadIdx.x;
    if (bid < P_CNT) {
        // ---- count: LDS histogram of dst>>9 over this block's edge chunk ----
        __shared__ unsigned h[256];
        for (int i = tid; i < NB; i += 256) h[i] = 0u;
        __syncthreads();
        int s = bid * per;
        int e1 = min(E, s + per);
        for (int e = s + tid; e < e1; e += 256)
            atomicAdd(&h[((unsigned)dst[e]) >> BKT_SHIFT], 1u);
        __syncthreads();
        for (int i = tid; i < NB; i += 256)
            histT[(size_t)i * P_CNT + bid] = h[i];
    } else if (bid < P_CNT + XB) {
        // ---- convert x -> bf16 (8 elems/thread) ----
        int t = (bid - P_CNT) * 256 + tid;
        const float4* src = (const float4*)(x) + (size_t)t * 2;
        float4 a = src[0], b = src[1];
        uint4 o;
        o.x = f2bf(a.x) | ((unsigned)f2bf(a.y) << 16);
        o.y = f2bf(a.z) | ((unsigned)f2bf(a.w) << 16);
        o.z = f2bf(b.x) | ((unsigned)f2bf(b.y) << 16);
        o.w = f2bf(b.z) | ((unsigned)f2bf(b.w) << 16);
        ((uint4*)xb)[t] = o;
    } else {
        // ---- weight prep + BN constants ----
        int idx = (bid - P_CNT - XB) * 256 + tid;
        if (idx < 128 * 256) {
            int n = idx >> 8, k = idx & 255;
            float w = (k < 128) ? W1l[n * 128 + k] : W1r[n * 128 + (k - 128)];
            Wb1[idx] = f2bf(w);
        }
        if (idx < 128 * 128) {
            int n = idx >> 7, k = idx & 127;
            float w = (n < 64) ? W2l[n * 128 + k] : W2r[(n - 64) * 128 + k];
            Wb2[idx] = f2bf(w);
        }
        if (idx < 128) {
            float sc = rsqrtf(var[idx] + BN_EPS) * g[idx];
            bnsc[idx] = sc;
            bnsh[idx] = sc * (b1[idx] - mu[idx]) + bt[idx];
            cb2[idx] = (idx < 64) ? 0.f : b2[idx - 64];
        }
    }
}

// ---------------- per-block exclusive scan, stride-1 input ------------------
__global__ void scan_block_c(const unsigned* __restrict__ in, unsigned* __restrict__ excl,
                             unsigned* __restrict__ partials, int M) {
    __shared__ unsigned buf[256];
    int i = blockIdx.x * 256 + threadIdx.x;
    unsigned v = (i < M) ? in[i] : 0u;
    buf[threadIdx.x] = v;
    __syncthreads();
    for (int off = 1; off < 256; off <<= 1) {
        unsigned t = (threadIdx.x >= (unsigned)off) ? buf[threadIdx.x - off] : 0u;
        __syncthreads();
        buf[threadIdx.x] += t;
        __syncthreads();
    }
    if (i < M) excl[i] = buf[threadIdx.x] - v;
    if (threadIdx.x == 255) partials[blockIdx.x] = buf[255];
}

// ---------------- finish: each block reduces partials[0..b-1] itself ---------
__global__ void scan_finish(unsigned* __restrict__ arr,
                            const unsigned* __restrict__ partials, int M, int E) {
    __shared__ unsigned red[256];
    int b = blockIdx.x;
    unsigned s = 0;
    for (int t = threadIdx.x; t < b; t += 256) s += partials[t];
    red[threadIdx.x] = s;
    __syncthreads();
    for (int off = 128; off > 0; off >>= 1) {
        if ((int)threadIdx.x < off) red[threadIdx.x] += red[threadIdx.x + off];
        __syncthreads();
    }
    unsigned base = red[0];
    int i = b * 256 + threadIdx.x;
    if (i < M) arr[i] += base;
    if (i == 0) arr[M] = (unsigned)E;   // uniform bucket-end for the last bucket
}

// ---------------- scatter edges into coarse buckets (LDS offsets) ------------
__global__ __launch_bounds__(256) void scatter_bucket(
    const int* __restrict__ src, const int* __restrict__ dst, int E, int per, int NB,
    const unsigned* __restrict__ hexcl, unsigned* __restrict__ buck)
{
    __shared__ unsigned cnt[256];
    const int p = blockIdx.x, tid = threadIdx.x;
    for (int i = tid; i < NB; i += 256) cnt[i] = hexcl[(size_t)i * P_CNT + p];
    __syncthreads();
    int s = p * per, e1 = min(E, s + per);
    for (int e = s + tid; e < e1; e += 256) {
        unsigned d = (unsigned)dst[e];
        unsigned pos = atomicAdd(&cnt[d >> BKT_SHIFT], 1u);
        buck[pos] = ((unsigned)src[e] << BKT_SHIFT) | (d & (BKT_NODES - 1u));
    }
}

// ---------------- per-bucket CSR: 512-node LDS hist + scan -> row_start/csr --
__global__ __launch_bounds__(512) void bucket_csr(
    const unsigned* __restrict__ buck, const unsigned* __restrict__ hexcl,
    unsigned* __restrict__ row_start, unsigned* __restrict__ csr_src, int N, int E)
{
    __shared__ unsigned h[BKT_NODES];
    __shared__ unsigned sc[BKT_NODES];
    const int b = blockIdx.x, tid = threadIdx.x;
    const unsigned bs = hexcl[(size_t)b * P_CNT];
    const unsigned be = hexcl[(size_t)(b + 1) * P_CNT];
    h[tid] = 0u;
    __syncthreads();
    for (unsigned e = bs + tid; e < be; e += BKT_NODES)
        atomicAdd(&h[buck[e] & (BKT_NODES - 1u)], 1u);
    __syncthreads();
    unsigned v = h[tid];
    sc[tid] = v;
    __syncthreads();
    for (int off = 1; off < BKT_NODES; off <<= 1) {
        unsigned t = (tid >= off) ? sc[tid - off] : 0u;
        __syncthreads();
        sc[tid] += t;
        __syncthreads();
    }
    unsigned pos0 = bs + sc[tid] - v;   // global CSR start for this node
    int node = b * BKT_NODES + tid;
    if (node < N) row_start[node] = pos0;
    h[tid] = pos0;                      // reuse as running position counters
    __syncthreads();
    for (unsigned e = bs + tid; e < be; e += BKT_NODES) {
        unsigned pk = buck[e];
        unsigned pos = atomicAdd(&h[pk & (BKT_NODES - 1u)], 1u);
        csr_src[pos] = pk >> BKT_SHIFT;
    }
    if (b == 0 && tid == 0) row_start[N] = (unsigned)E;
}

// ---------------- gather + mean, XCD-split by 128B feature half --------------
// Each 256B xb row = 2 cache LINES (feats 0-63 / 64-127). With round-robin
// dispatch (xcd = bid&7), half = (bid>>2)&1 pins XCDs 0-3 to half 0 and
// XCDs 4-7 to half 1 -> each XCD's L2 only touches HALF of xb's lines.
// (Splitting below 128B line granularity REGRESSES: r4 measured 2.1x fetch.)
// 8 lanes/node-half, 32 node-jobs/block, unroll 8.
__global__ __launch_bounds__(256) void gather_mean_bf(const unsigned short* __restrict__ xb,
                                                      const unsigned* __restrict__ row_start,
                                                      const unsigned* __restrict__ csr_src,
                                                      unsigned short* __restrict__ aggb,
                                                      int N, int NBLK) {
    const int bid = blockIdx.x;
    const int half = (bid >> 2) & 1;                  // constant per XCD group
    const int nodeblk = (bid & 3) | ((bid >> 3) << 2);
    if (nodeblk >= NBLK) return;
    const int node = nodeblk * 32 + (threadIdx.x >> 3);
    if (node >= N) return;
    const int f = half * 64 + (threadIdx.x & 7) * 8;
    unsigned s0 = row_start[node], s1 = row_start[node + 1];
    float acc[8];
#pragma unroll
    for (int i = 0; i < 8; i++) acc[i] = 0.f;
    unsigned i = s0;
    for (; i + 8 <= s1; i += 8) {
        unsigned i0 = csr_src[i + 0], i1 = csr_src[i + 1];
        unsigned i2 = csr_src[i + 2], i3 = csr_src[i + 3];
        unsigned i4 = csr_src[i + 4], i5 = csr_src[i + 5];
        unsigned i6 = csr_src[i + 6], i7 = csr_src[i + 7];
        uint4 d0 = *(const uint4*)(xb + (size_t)i0 * 128 + f);
        uint4 d1 = *(const uint4*)(xb + (size_t)i1 * 128 + f);
        uint4 d2 = *(const uint4*)(xb + (size_t)i2 * 128 + f);
        uint4 d3 = *(const uint4*)(xb + (size_t)i3 * 128 + f);
        uint4 d4 = *(const uint4*)(xb + (size_t)i4 * 128 + f);
        uint4 d5 = *(const uint4*)(xb + (size_t)i5 * 128 + f);
        uint4 d6 = *(const uint4*)(xb + (size_t)i6 * 128 + f);
        uint4 d7 = *(const uint4*)(xb + (size_t)i7 * 128 + f);
        acc8(acc, d0); acc8(acc, d1); acc8(acc, d2); acc8(acc, d3);
        acc8(acc, d4); acc8(acc, d5); acc8(acc, d6); acc8(acc, d7);
    }
    if (i + 4 <= s1) {
        unsigned i0 = csr_src[i + 0], i1 = csr_src[i + 1];
        unsigned i2 = csr_src[i + 2], i3 = csr_src[i + 3];
        uint4 d0 = *(const uint4*)(xb + (size_t)i0 * 128 + f);
        uint4 d1 = *(const uint4*)(xb + (size_t)i1 * 128 + f);
        uint4 d2 = *(const uint4*)(xb + (size_t)i2 * 128 + f);
        uint4 d3 = *(const uint4*)(xb + (size_t)i3 * 128 + f);
        acc8(acc, d0); acc8(acc, d1); acc8(acc, d2); acc8(acc, d3);
        i += 4;
    }
    if (i + 2 <= s1) {
        unsigned i0 = csr_src[i + 0], i1 = csr_src[i + 1];
        uint4 d0 = *(const uint4*)(xb + (size_t)i0 * 128 + f);
        uint4 d1 = *(const uint4*)(xb + (size_t)i1 * 128 + f);
        acc8(acc, d0); acc8(acc, d1);
        i += 2;
    }
    if (i < s1) {
        unsigned i0 = csr_src[i];
        uint4 d0 = *(const uint4*)(xb + (size_t)i0 * 128 + f);
        acc8(acc, d0);
    }
    float inv = (s1 > s0) ? 1.0f / (float)(s1 - s0) : 0.f;
    uint4 o;
    o.x = f2bf(acc[0] * inv) | ((unsigned)f2bf(acc[1] * inv) << 16);
    o.y = f2bf(acc[2] * inv) | ((unsigned)f2bf(acc[3] * inv) << 16);
    o.z = f2bf(acc[4] * inv) | ((unsigned)f2bf(acc[5] * inv) << 16);
    o.w = f2bf(acc[6] * inv) | ((unsigned)f2bf(acc[7] * inv) << 16);
    *(uint4*)(aggb + (size_t)node * 128 + f) = o;
}

// ---------------- dense: layer1 GEMM+BN/ReLU + layer2 GEMM, LDS weights ------
// r3 LDS-staged structure (r6's direct-global weight reads were 2.5x slower:
// per-lane scattered operand reads lose to coalesced stage + LDS).
// T14 async-stage split: each stage's 8x16B weight loads are issued into
// REGISTERS one phase early (under the previous MFMA block / a-frag loads);
// only the ds_write sits between barriers. Same layout, same fragment bytes.
__global__ __launch_bounds__(256) void sage_dense(
    const unsigned short* __restrict__ aggb,
    const unsigned short* __restrict__ xb,
    const unsigned short* __restrict__ Wb1,   // [128][256]
    const unsigned short* __restrict__ Wb2,   // [128][128]
    const float* __restrict__ bnsc, const float* __restrict__ bnsh,
    const float* __restrict__ cb2,
    unsigned short* __restrict__ uvb, int N)
{
    __shared__ __align__(16) unsigned short As[64 * 128];   // 16 KB (h transpose)
    __shared__ __align__(16) unsigned short Bs[128 * 128];  // 32 KB
    uint4* AsV = (uint4*)As;
    uint4* BsV = (uint4*)Bs;

    const int tid = threadIdx.x;
    const int wave = tid >> 6;
    const int lane = tid & 63;
    const int mr = lane & 15;
    const int q = lane >> 4;
    const int m0 = blockIdx.x * 64;
    const int mw = m0 + wave * 16 + mr;
    const bool mv = mw < N;

    const int sn = tid >> 4;            // staging row (n) for this thread
    const int sc_ = tid & 15;           // staging chunk (c)
    const int sslot = sn * 16 + (sc_ ^ (sn & 15));   // swizzled BsV slot

    // ---- issue stage-0 weight loads (Wb1 cols 0..127) into regs FIRST ----
    uint4 w[8];
#pragma unroll
    for (int i = 0; i < 8; i++) {
        int n = sn + i * 16;
        w[i] = *(const uint4*)(Wb1 + (size_t)n * 256 + sc_ * 8);
    }

    // ---- a-fragment loads (independent, overlap the stage writes) ----
    FragU ag[4], ax[4];
#pragma unroll
    for (int kc4 = 0; kc4 < 4; kc4++) {
        ag[kc4].u = make_uint4(0u, 0u, 0u, 0u);
        ax[kc4].u = make_uint4(0u, 0u, 0u, 0u);
        if (mv) {
            ag[kc4].u = *(const uint4*)(aggb + (size_t)mw * 128 + kc4 * 32 + q * 8);
            ax[kc4].u = *(const uint4*)(xb + (size_t)mw * 128 + kc4 * 32 + q * 8);
        }
    }

    // ---- write stage 0 ----
#pragma unroll
    for (int i = 0; i < 8; i++) BsV[sslot + i * 256] = w[i];
    __syncthreads();

    // ---- issue stage-1 loads (Wb1 cols 128..255) under MFMA half-0 ----
#pragma unroll
    for (int i = 0; i < 8; i++) {
        int n = sn + i * 16;
        w[i] = *(const uint4*)(Wb1 + (size_t)n * 256 + 128 + sc_ * 8);
    }

    f4frag acc[8];
#pragma unroll
    for (int j = 0; j < 8; j++)
#pragma unroll
        for (int r = 0; r < 4; r++) acc[j][r] = 0.f;

#pragma unroll
    for (int kc4 = 0; kc4 < 4; kc4++) {
#pragma unroll
        for (int j = 0; j < 8; j++) {
            FragU b;
            b.u = BsV[(j * 16 + mr) * 16 + ((kc4 * 4 + q) ^ mr)];
            acc[j] = __builtin_amdgcn_mfma_f32_16x16x32_bf16(ag[kc4].v, b.v, acc[j], 0, 0, 0);
        }
    }
    __syncthreads();

    // ---- write stage 1 ----
#pragma unroll
    for (int i = 0; i < 8; i++) BsV[sslot + i * 256] = w[i];
    __syncthreads();

    // ---- issue stage-2 loads (Wb2) under MFMA half-1 ----
#pragma unroll
    for (int i = 0; i < 8; i++) {
        int n = sn + i * 16;
        w[i] = *(const uint4*)(Wb2 + (size_t)n * 128 + sc_ * 8);
    }

#pragma unroll
    for (int kc4 = 0; kc4 < 4; kc4++) {
#pragma unroll
        for (int j = 0; j < 8; j++) {
            FragU b;
            b.u = BsV[(j * 16 + mr) * 16 + ((kc4 * 4 + q) ^ mr)];
            acc[j] = __builtin_amdgcn_mfma_f32_16x16x32_bf16(ax[kc4].v, b.v, acc[j], 0, 0, 0);
        }
    }

    // BN + ReLU -> As (h transposed, XOR-swizzled)
#pragma unroll
    for (int j = 0; j < 8; j++) {
        int n = j * 16 + mr;
        float sc = bnsc[n], sh = bnsh[n];
        int cn = n >> 3;
#pragma unroll
        for (int r = 0; r < 4; r++) {
            int ml = wave * 16 + q * 4 + r;
            float v = fmaxf(acc[j][r] * sc + sh, 0.f);
            As[(ml * 16 + (cn ^ (ml & 15))) * 8 + (n & 7)] = f2bf(v);
        }
    }
    __syncthreads();

    // ---- write stage 2 ----
#pragma unroll
    for (int i = 0; i < 8; i++) BsV[sslot + i * 256] = w[i];
    __syncthreads();

    // layer-2: h @ [W2l|W2r]^T
#pragma unroll
    for (int j = 0; j < 8; j++)
#pragma unroll
        for (int r = 0; r < 4; r++) acc[j][r] = 0.f;
    const int arow = (wave * 16 + mr) * 16;
#pragma unroll
    for (int kc4 = 0; kc4 < 4; kc4++) {
        FragU a;
        a.u = AsV[arow + ((kc4 * 4 + q) ^ mr)];
#pragma unroll
        for (int j = 0; j < 8; j++) {
            FragU b;
            b.u = BsV[(j * 16 + mr) * 16 + ((kc4 * 4 + q) ^ mr)];
            acc[j] = __builtin_amdgcn_mfma_f32_16x16x32_bf16(a.v, b.v, acc[j], 0, 0, 0);
        }
    }

#pragma unroll
    for (int j = 0; j < 8; j++) {
        int n = j * 16 + mr;
        float cb = cb2[n];
#pragma unroll
        for (int r = 0; r < 4; r++) {
            int mrow = m0 + wave * 16 + q * 4 + r;
            if (mrow < N)
                uvb[(size_t)mrow * 128 + n] = f2bf(acc[j][r] + cb);
        }
    }
}

// ---------------- layer-2 finish: out = mean_agg(u) + v, fp32, unroll 8 ------
__global__ __launch_bounds__(256) void gather_out_bf(const unsigned short* __restrict__ uvb,
                                                     const unsigned* __restrict__ row_start,
                                                     const unsigned* __restrict__ csr_src,
                                                     float* __restrict__ out, int N) {
    int gid = blockIdx.x * 256 + threadIdx.x;
    int node = gid >> 3;
    if (node >= N) return;
    int f = (threadIdx.x & 7) * 8;
    unsigned s0 = row_start[node], s1 = row_start[node + 1];
    float acc[8];
#pragma unroll
    for (int i = 0; i < 8; i++) acc[i] = 0.f;
    unsigned i = s0;
    for (; i + 8 <= s1; i += 8) {
        unsigned i0 = csr_src[i + 0], i1 = csr_src[i + 1];
        unsigned i2 = csr_src[i + 2], i3 = csr_src[i + 3];
        unsigned i4 = csr_src[i + 4], i5 = csr_src[i + 5];
        unsigned i6 = csr_src[i + 6], i7 = csr_src[i + 7];
        uint4 d0 = *(const uint4*)(uvb + (size_t)i0 * 128 + f);
        uint4 d1 = *(const uint4*)(uvb + (size_t)i1 * 128 + f);
        uint4 d2 = *(const uint4*)(uvb + (size_t)i2 * 128 + f);
        uint4 d3 = *(const uint4*)(uvb + (size_t)i3 * 128 + f);
        uint4 d4 = *(const uint4*)(uvb + (size_t)i4 * 128 + f);
        uint4 d5 = *(const uint4*)(uvb + (size_t)i5 * 128 + f);
        uint4 d6 = *(const uint4*)(uvb + (size_t)i6 * 128 + f);
        uint4 d7 = *(const uint4*)(uvb + (size_t)i7 * 128 + f);
        acc8(acc, d0); acc8(acc, d1); acc8(acc, d2); acc8(acc, d3);
        acc8(acc, d4); acc8(acc, d5); acc8(acc, d6); acc8(acc, d7);
    }
    if (i + 4 <= s1) {
        unsigned i0 = csr_src[i + 0], i1 = csr_src[i + 1];
        unsigned i2 = csr_src[i + 2], i3 = csr_src[i + 3];
        uint4 d0 = *(const uint4*)(uvb + (size_t)i0 * 128 + f);
        uint4 d1 = *(const uint4*)(uvb + (size_t)i1 * 128 + f);
        uint4 d2 = *(const uint4*)(uvb + (size_t)i2 * 128 + f);
        uint4 d3 = *(const uint4*)(uvb + (size_t)i3 * 128 + f);
        acc8(acc, d0); acc8(acc, d1); acc8(acc, d2); acc8(acc, d3);
        i += 4;
    }
    if (i + 2 <= s1) {
        unsigned i0 = csr_src[i + 0], i1 = csr_src[i + 1];
        uint4 d0 = *(const uint4*)(uvb + (size_t)i0 * 128 + f);
        uint4 d1 = *(const uint4*)(uvb + (size_t)i1 * 128 + f);
        acc8(acc, d0); acc8(acc, d1);
        i += 2;
    }
    if (i < s1) {
        unsigned i0 = csr_src[i];
        uint4 d0 = *(const uint4*)(uvb + (size_t)i0 * 128 + f);
        acc8(acc, d0);
    }
    float inv = (s1 > s0) ? 1.0f / (float)(s1 - s0) : 0.f;
    uint4 dv = *(const uint4*)(uvb + (size_t)node * 128 + 64 + f);
    float vv[8];
    unpack2(dv.x, vv[0], vv[1]);
    unpack2(dv.y, vv[2], vv[3]);
    unpack2(dv.z, vv[4], vv[5]);
    unpack2(dv.w, vv[6], vv[7]);
    float4 o0 = make_float4(acc[0] * inv + vv[0], acc[1] * inv + vv[1],
                            acc[2] * inv + vv[2], acc[3] * inv + vv[3]);
    float4 o1 = make_float4(acc[4] * inv + vv[4], acc[5] * inv + vv[5],
                            acc[6] * inv + vv[6], acc[7] * inv + vv[7]);
    *(float4*)(out + (size_t)node * 64 + f) = o0;
    *(float4*)(out + (size_t)node * 64 + f + 4) = o1;
}

extern "C" void kernel_launch(void* const* d_in, const int* in_sizes, int n_in,
                              void* d_out, int out_size, void* d_ws, size_t ws_size,
                              hipStream_t stream) {
    const float* x     = (const float*)d_in[0];
    const int*   edge  = (const int*)d_in[1];
    const float* W1l   = (const float*)d_in[2];
    const float* b1    = (const float*)d_in[3];
    const float* W1r   = (const float*)d_in[4];
    const float* gamma = (const float*)d_in[5];
    const float* beta  = (const float*)d_in[6];
    const float* mean  = (const float*)d_in[7];
    const float* var   = (const float*)d_in[8];
    const float* W2l   = (const float*)d_in[9];
    const float* b2    = (const float*)d_in[10];
    const float* W2r   = (const float*)d_in[11];

    const int N = in_sizes[0] / FEAT;
    const int E = in_sizes[1] / 2;
    const int* srcI = edge;
    const int* dstI = edge + E;

    const int NB  = (N + BKT_NODES - 1) >> BKT_SHIFT;  // coarse buckets (196)
    const int M   = NB * P_CNT;                        // hist entries (200704)
    const int per = (E + P_CNT - 1) / P_CNT;           // edges per chunk block

    unsigned short* uvb  = (unsigned short*)d_ws;      // N*128
    unsigned short* aggb = uvb + (size_t)N * 128;      // N*128
    unsigned short* xb   = aggb + (size_t)N * 128;     // N*128
    unsigned short* Wb1  = xb + (size_t)N * 128;       // 128*256
    unsigned short* Wb2  = Wb1 + 256 * 128;            // 128*128
    float* bnsc = (float*)(Wb2 + 128 * 128);           // 128
    float* bnsh = bnsc + 128;                          // 128
    float* cb2  = bnsh + 128;                          // 128
    unsigned* histT     = (unsigned*)(cb2 + 128);      // M+1
    unsigned* hexcl     = histT + (M + 1);             // M+1
    unsigned* partials  = hexcl + (M + 1);             // 1024
    unsigned* row_start = partials + 1024;             // N+1
    unsigned* buck      = row_start + (N + 1);         // E (packed src|dstlow)
    unsigned* csr_src   = buck + E;                    // E

    float* outp = (float*)d_out;

    // front: LDS-hist count | convert | prep, one dispatch, no memset needed
    const int total8 = N * FEAT / 8;
    const int XB = (total8 + 255) / 256;
    const int PB = (128 * 256 + 255) / 256;            // weight-prep blocks
    front2<<<P_CNT + XB + PB, 256, 0, stream>>>(
        dstI, E, per, NB, histT, x, xb, XB,
        W1l, W1r, W2l, W2r, b1, gamma, beta, mean, var, b2,
        Wb1, Wb2, bnsc, bnsh, cb2);

    scan_block_c<<<M / 256, 256, 0, stream>>>(histT, hexcl, partials, M);
    scan_finish<<<M / 256, 256, 0, stream>>>(hexcl, partials, M, E);
    scatter_bucket<<<P_CNT, 256, 0, stream>>>(srcI, dstI, E, per, NB, hexcl, buck);
    bucket_csr<<<NB, BKT_NODES, 0, stream>>>(buck, hexcl, row_start, csr_src, N, E);

    // gather_mean: 128B-half XCD split; 32 nodes/block, 2 halves
    {
        const int NBLK = (N + 31) / 32;                 // node-blocks per half
        const int G = 8 * ((2 * NBLK + 7) / 8);         // both halves, xcd-aligned
        gather_mean_bf<<<G, 256, 0, stream>>>(xb, row_start, csr_src, aggb, N, NBLK);
    }
    sage_dense<<<(N + 63) / 64, 256, 0, stream>>>(aggb, xb, Wb1, Wb2, bnsc, bnsh, cb2, uvb, N);
    gather_out_bf<<<(N * 8 + 255) / 256, 256, 0, stream>>>(uvb, row_start, csr_src, outp, N);
}

// Round 9
// 275.119 us; speedup vs baseline: 1.2368x; 1.1348x over previous
//
#include <hip/hip_runtime.h>

#define FEAT 128
#define BN_EPS 1e-5f
#define P_CNT 1024            // edge-chunk blocks for count/scatter
#define BKT_SHIFT 9           // 512 nodes per coarse bucket
#define BKT_NODES 512

typedef __attribute__((ext_vector_type(8))) short s8frag;
typedef __attribute__((ext_vector_type(4))) float f4frag;

union FragU { uint4 u; s8frag v; };

__device__ __forceinline__ unsigned short f2bf(float f) {
    unsigned u = __float_as_uint(f);
    unsigned r = (u + 0x7fffu + ((u >> 16) & 1u)) >> 16;
    return (unsigned short)r;
}
__device__ __forceinline__ void unpack2(unsigned d, float& lo, float& hi) {
    lo = __uint_as_float(d << 16);
    hi = __uint_as_float(d & 0xffff0000u);
}
__device__ __forceinline__ void acc8(float* acc, uint4 d) {
    float l, h;
    unpack2(d.x, l, h); acc[0] += l; acc[1] += h;
    unpack2(d.y, l, h); acc[2] += l; acc[3] += h;
    unpack2(d.z, l, h); acc[4] += l; acc[5] += h;
    unpack2(d.w, l, h); acc[6] += l; acc[7] += h;
}

// ---------------- FRONT: LDS-histogram count (A) | x->bf16 (B) | weight prep (C)
__global__ __launch_bounds__(256) void front2(
    const int* __restrict__ dst, int E, int per, int NB,
    unsigned* __restrict__ histT,               // [NB][P_CNT] transposed hist
    const float* __restrict__ x, unsigned short* __restrict__ xb, int XB,
    const float* __restrict__ W1l, const float* __restrict__ W1r,
    const float* __restrict__ W2l, const float* __restrict__ W2r,
    const float* __restrict__ b1, const float* __restrict__ g,
    const float* __restrict__ bt, const float* __restrict__ mu,
    const float* __restrict__ var, const float* __restrict__ b2,
    unsigned short* __restrict__ Wb1, unsigned short* __restrict__ Wb2,
    float* __restrict__ bnsc, float* __restrict__ bnsh, float* __restrict__ cb2)
{
    const int bid = blockIdx.x;
    const int tid = threadIdx.x;
    if (bid < P_CNT) {
        // ---- count: LDS histogram of dst>>9 over this block's edge chunk ----
        __shared__ unsigned h[256];
        for (int i = tid; i < NB; i += 256) h[i] = 0u;
        __syncthreads();
        int s = bid * per;
        int e1 = min(E, s + per);
        for (int e = s + tid; e < e1; e += 256)
            atomicAdd(&h[((unsigned)dst[e]) >> BKT_SHIFT], 1u);
        __syncthreads();
        for (int i = tid; i < NB; i += 256)
            histT[(size_t)i * P_CNT + bid] = h[i];
    } else if (bid < P_CNT + XB) {
        // ---- convert x -> bf16 (8 elems/thread) ----
        int t = (bid - P_CNT) * 256 + tid;
        const float4* src = (const float4*)(x) + (size_t)t * 2;
        float4 a = src[0], b = src[1];
        uint4 o;
        o.x = f2bf(a.x) | ((unsigned)f2bf(a.y) << 16);
        o.y = f2bf(a.z) | ((unsigned)f2bf(a.w) << 16);
        o.z = f2bf(b.x) | ((unsigned)f2bf(b.y) << 16);
        o.w = f2bf(b.z) | ((unsigned)f2bf(b.w) << 16);
        ((uint4*)xb)[t] = o;
    } else {
        // ---- weight prep + BN constants ----
        int idx = (bid - P_CNT - XB) * 256 + tid;
        if (idx < 128 * 256) {
            int n = idx >> 8, k = idx & 255;
            float w = (k < 128) ? W1l[n * 128 + k] : W1r[n * 128 + (k - 128)];
            Wb1[idx] = f2bf(w);
        }
        if (idx < 128 * 128) {
            int n = idx >> 7, k = idx & 127;
            float w = (n < 64) ? W2l[n * 128 + k] : W2r[(n - 64) * 128 + k];
            Wb2[idx] = f2bf(w);
        }
        if (idx < 128) {
            float sc = rsqrtf(var[idx] + BN_EPS) * g[idx];
            bnsc[idx] = sc;
            bnsh[idx] = sc * (b1[idx] - mu[idx]) + bt[idx];
            cb2[idx] = (idx < 64) ? 0.f : b2[idx - 64];
        }
    }
}

// ---------------- per-block exclusive scan, stride-1 input ------------------
__global__ void scan_block_c(const unsigned* __restrict__ in, unsigned* __restrict__ excl,
                             unsigned* __restrict__ partials, int M) {
    __shared__ unsigned buf[256];
    int i = blockIdx.x * 256 + threadIdx.x;
    unsigned v = (i < M) ? in[i] : 0u;
    buf[threadIdx.x] = v;
    __syncthreads();
    for (int off = 1; off < 256; off <<= 1) {
        unsigned t = (threadIdx.x >= (unsigned)off) ? buf[threadIdx.x - off] : 0u;
        __syncthreads();
        buf[threadIdx.x] += t;
        __syncthreads();
    }
    if (i < M) excl[i] = buf[threadIdx.x] - v;
    if (threadIdx.x == 255) partials[blockIdx.x] = buf[255];
}

// ---------------- finish: each block reduces partials[0..b-1] itself ---------
__global__ void scan_finish(unsigned* __restrict__ arr,
                            const unsigned* __restrict__ partials, int M, int E) {
    __shared__ unsigned red[256];
    int b = blockIdx.x;
    unsigned s = 0;
    for (int t = threadIdx.x; t < b; t += 256) s += partials[t];
    red[threadIdx.x] = s;
    __syncthreads();
    for (int off = 128; off > 0; off >>= 1) {
        if ((int)threadIdx.x < off) red[threadIdx.x] += red[threadIdx.x + off];
        __syncthreads();
    }
    unsigned base = red[0];
    int i = b * 256 + threadIdx.x;
    if (i < M) arr[i] += base;
    if (i == 0) arr[M] = (unsigned)E;   // uniform bucket-end for the last bucket
}

// ---------------- scatter edges into coarse buckets (LDS offsets) ------------
__global__ __launch_bounds__(256) void scatter_bucket(
    const int* __restrict__ src, const int* __restrict__ dst, int E, int per, int NB,
    const unsigned* __restrict__ hexcl, unsigned* __restrict__ buck)
{
    __shared__ unsigned cnt[256];
    const int p = blockIdx.x, tid = threadIdx.x;
    for (int i = tid; i < NB; i += 256) cnt[i] = hexcl[(size_t)i * P_CNT + p];
    __syncthreads();
    int s = p * per, e1 = min(E, s + per);
    for (int e = s + tid; e < e1; e += 256) {
        unsigned d = (unsigned)dst[e];
        unsigned pos = atomicAdd(&cnt[d >> BKT_SHIFT], 1u);
        buck[pos] = ((unsigned)src[e] << BKT_SHIFT) | (d & (BKT_NODES - 1u));
    }
}

// ---------------- per-bucket CSR: 512-node LDS hist + scan -> row_start/csr --
__global__ __launch_bounds__(512) void bucket_csr(
    const unsigned* __restrict__ buck, const unsigned* __restrict__ hexcl,
    unsigned* __restrict__ row_start, unsigned* __restrict__ csr_src, int N, int E)
{
    __shared__ unsigned h[BKT_NODES];
    __shared__ unsigned sc[BKT_NODES];
    const int b = blockIdx.x, tid = threadIdx.x;
    const unsigned bs = hexcl[(size_t)b * P_CNT];
    const unsigned be = hexcl[(size_t)(b + 1) * P_CNT];
    h[tid] = 0u;
    __syncthreads();
    for (unsigned e = bs + tid; e < be; e += BKT_NODES)
        atomicAdd(&h[buck[e] & (BKT_NODES - 1u)], 1u);
    __syncthreads();
    unsigned v = h[tid];
    sc[tid] = v;
    __syncthreads();
    for (int off = 1; off < BKT_NODES; off <<= 1) {
        unsigned t = (tid >= off) ? sc[tid - off] : 0u;
        __syncthreads();
        sc[tid] += t;
        __syncthreads();
    }
    unsigned pos0 = bs + sc[tid] - v;   // global CSR start for this node
    int node = b * BKT_NODES + tid;
    if (node < N) row_start[node] = pos0;
    h[tid] = pos0;                      // reuse as running position counters
    __syncthreads();
    for (unsigned e = bs + tid; e < be; e += BKT_NODES) {
        unsigned pk = buck[e];
        unsigned pos = atomicAdd(&h[pk & (BKT_NODES - 1u)], 1u);
        csr_src[pos] = pk >> BKT_SHIFT;
    }
    if (b == 0 && tid == 0) row_start[N] = (unsigned)E;
}

// ---------------- gather + mean, XCD-split by 128B feature half --------------
// Each 256B xb row = 2 cache LINES (feats 0-63 / 64-127). With round-robin
// dispatch (xcd = bid&7), half = (bid>>2)&1 pins XCDs 0-3 to half 0 and
// XCDs 4-7 to half 1 -> each XCD's L2 only touches HALF of xb's lines.
// (Splitting below 128B line granularity REGRESSES: r4 measured 2.1x fetch.)
// 8 lanes/node-half, 32 node-jobs/block, unroll 8.
__global__ __launch_bounds__(256) void gather_mean_bf(const unsigned short* __restrict__ xb,
                                                      const unsigned* __restrict__ row_start,
                                                      const unsigned* __restrict__ csr_src,
                                                      unsigned short* __restrict__ aggb,
                                                      int N, int NBLK) {
    const int bid = blockIdx.x;
    const int half = (bid >> 2) & 1;                  // constant per XCD group
    const int nodeblk = (bid & 3) | ((bid >> 3) << 2);
    if (nodeblk >= NBLK) return;
    const int node = nodeblk * 32 + (threadIdx.x >> 3);
    if (node >= N) return;
    const int f = half * 64 + (threadIdx.x & 7) * 8;
    unsigned s0 = row_start[node], s1 = row_start[node + 1];
    float acc[8];
#pragma unroll
    for (int i = 0; i < 8; i++) acc[i] = 0.f;
    unsigned i = s0;
    for (; i + 8 <= s1; i += 8) {
        unsigned i0 = csr_src[i + 0], i1 = csr_src[i + 1];
        unsigned i2 = csr_src[i + 2], i3 = csr_src[i + 3];
        unsigned i4 = csr_src[i + 4], i5 = csr_src[i + 5];
        unsigned i6 = csr_src[i + 6], i7 = csr_src[i + 7];
        uint4 d0 = *(const uint4*)(xb + (size_t)i0 * 128 + f);
        uint4 d1 = *(const uint4*)(xb + (size_t)i1 * 128 + f);
        uint4 d2 = *(const uint4*)(xb + (size_t)i2 * 128 + f);
        uint4 d3 = *(const uint4*)(xb + (size_t)i3 * 128 + f);
        uint4 d4 = *(const uint4*)(xb + (size_t)i4 * 128 + f);
        uint4 d5 = *(const uint4*)(xb + (size_t)i5 * 128 + f);
        uint4 d6 = *(const uint4*)(xb + (size_t)i6 * 128 + f);
        uint4 d7 = *(const uint4*)(xb + (size_t)i7 * 128 + f);
        acc8(acc, d0); acc8(acc, d1); acc8(acc, d2); acc8(acc, d3);
        acc8(acc, d4); acc8(acc, d5); acc8(acc, d6); acc8(acc, d7);
    }
    if (i + 4 <= s1) {
        unsigned i0 = csr_src[i + 0], i1 = csr_src[i + 1];
        unsigned i2 = csr_src[i + 2], i3 = csr_src[i + 3];
        uint4 d0 = *(const uint4*)(xb + (size_t)i0 * 128 + f);
        uint4 d1 = *(const uint4*)(xb + (size_t)i1 * 128 + f);
        uint4 d2 = *(const uint4*)(xb + (size_t)i2 * 128 + f);
        uint4 d3 = *(const uint4*)(xb + (size_t)i3 * 128 + f);
        acc8(acc, d0); acc8(acc, d1); acc8(acc, d2); acc8(acc, d3);
        i += 4;
    }
    if (i + 2 <= s1) {
        unsigned i0 = csr_src[i + 0], i1 = csr_src[i + 1];
        uint4 d0 = *(const uint4*)(xb + (size_t)i0 * 128 + f);
        uint4 d1 = *(const uint4*)(xb + (size_t)i1 * 128 + f);
        acc8(acc, d0); acc8(acc, d1);
        i += 2;
    }
    if (i < s1) {
        unsigned i0 = csr_src[i];
        uint4 d0 = *(const uint4*)(xb + (size_t)i0 * 128 + f);
        acc8(acc, d0);
    }
    float inv = (s1 > s0) ? 1.0f / (float)(s1 - s0) : 0.f;
    uint4 o;
    o.x = f2bf(acc[0] * inv) | ((unsigned)f2bf(acc[1] * inv) << 16);
    o.y = f2bf(acc[2] * inv) | ((unsigned)f2bf(acc[3] * inv) << 16);
    o.z = f2bf(acc[4] * inv) | ((unsigned)f2bf(acc[5] * inv) << 16);
    o.w = f2bf(acc[6] * inv) | ((unsigned)f2bf(acc[7] * inv) << 16);
    *(uint4*)(aggb + (size_t)node * 128 + f) = o;
}

// ---------------- dense: layer1 GEMM+BN/ReLU + layer2 GEMM, LDS weights ------
// r3 staged structure (NO cross-barrier register prefetch: r7 spilled to
// scratch, WRITE_SIZE 25->143 MB, +32us). Amortization instead: 512 threads,
// 8 waves, 128 rows/block -> weight staging cost per row halves; LDS = 32KB
// As + 32KB Bs = 64KB -> 2 blocks/CU = 16 waves/CU (vs r3's 12).
__global__ __launch_bounds__(512) void sage_dense(
    const unsigned short* __restrict__ aggb,
    const unsigned short* __restrict__ xb,
    const unsigned short* __restrict__ Wb1,   // [128][256]
    const unsigned short* __restrict__ Wb2,   // [128][128]
    const float* __restrict__ bnsc, const float* __restrict__ bnsh,
    const float* __restrict__ cb2,
    unsigned short* __restrict__ uvb, int N)
{
    __shared__ __align__(16) unsigned short As[128 * 128];  // 32 KB (h transpose)
    __shared__ __align__(16) unsigned short Bs[128 * 128];  // 32 KB
    uint4* AsV = (uint4*)As;
    uint4* BsV = (uint4*)Bs;

    const int tid = threadIdx.x;
    const int wave = tid >> 6;          // 0..7
    const int lane = tid & 63;
    const int mr = lane & 15;
    const int q = lane >> 4;
    const int m0 = blockIdx.x * 128;
    const int mw = m0 + wave * 16 + mr;
    const bool mv = mw < N;

    FragU ag[4], ax[4];
#pragma unroll
    for (int kc4 = 0; kc4 < 4; kc4++) {
        ag[kc4].u = make_uint4(0u, 0u, 0u, 0u);
        ax[kc4].u = make_uint4(0u, 0u, 0u, 0u);
        if (mv) {
            ag[kc4].u = *(const uint4*)(aggb + (size_t)mw * 128 + kc4 * 32 + q * 8);
            ax[kc4].u = *(const uint4*)(xb + (size_t)mw * 128 + kc4 * 32 + q * 8);
        }
    }

#pragma unroll
    for (int i = 0; i < 4; i++) {
        int gch = tid + i * 512;
        int n = gch >> 4, c = gch & 15;
        BsV[n * 16 + (c ^ (n & 15))] = *(const uint4*)(Wb1 + (size_t)n * 256 + c * 8);
    }
    __syncthreads();

    f4frag acc[8];
#pragma unroll
    for (int j = 0; j < 8; j++)
#pragma unroll
        for (int r = 0; r < 4; r++) acc[j][r] = 0.f;

#pragma unroll
    for (int kc4 = 0; kc4 < 4; kc4++) {
#pragma unroll
        for (int j = 0; j < 8; j++) {
            FragU b;
            b.u = BsV[(j * 16 + mr) * 16 + ((kc4 * 4 + q) ^ mr)];
            acc[j] = __builtin_amdgcn_mfma_f32_16x16x32_bf16(ag[kc4].v, b.v, acc[j], 0, 0, 0);
        }
    }
    __syncthreads();

#pragma unroll
    for (int i = 0; i < 4; i++) {
        int gch = tid + i * 512;
        int n = gch >> 4, c = gch & 15;
        BsV[n * 16 + (c ^ (n & 15))] = *(const uint4*)(Wb1 + (size_t)n * 256 + 128 + c * 8);
    }
    __syncthreads();

#pragma unroll
    for (int kc4 = 0; kc4 < 4; kc4++) {
#pragma unroll
        for (int j = 0; j < 8; j++) {
            FragU b;
            b.u = BsV[(j * 16 + mr) * 16 + ((kc4 * 4 + q) ^ mr)];
            acc[j] = __builtin_amdgcn_mfma_f32_16x16x32_bf16(ax[kc4].v, b.v, acc[j], 0, 0, 0);
        }
    }

    // BN + ReLU -> As (h transposed, XOR-swizzled); ml in 0..127
#pragma unroll
    for (int j = 0; j < 8; j++) {
        int n = j * 16 + mr;
        float sc = bnsc[n], sh = bnsh[n];
        int cn = n >> 3;
#pragma unroll
        for (int r = 0; r < 4; r++) {
            int ml = wave * 16 + q * 4 + r;
            float v = fmaxf(acc[j][r] * sc + sh, 0.f);
            As[(ml * 16 + (cn ^ (ml & 15))) * 8 + (n & 7)] = f2bf(v);
        }
    }
    __syncthreads();

#pragma unroll
    for (int i = 0; i < 4; i++) {
        int gch = tid + i * 512;
        int n = gch >> 4, c = gch & 15;
        BsV[n * 16 + (c ^ (n & 15))] = *(const uint4*)(Wb2 + (size_t)n * 128 + c * 8);
    }
    __syncthreads();

    // layer-2: h @ [W2l|W2r]^T
#pragma unroll
    for (int j = 0; j < 8; j++)
#pragma unroll
        for (int r = 0; r < 4; r++) acc[j][r] = 0.f;
    const int arow = (wave * 16 + mr) * 16;
#pragma unroll
    for (int kc4 = 0; kc4 < 4; kc4++) {
        FragU a;
        a.u = AsV[arow + ((kc4 * 4 + q) ^ mr)];
#pragma unroll
        for (int j = 0; j < 8; j++) {
            FragU b;
            b.u = BsV[(j * 16 + mr) * 16 + ((kc4 * 4 + q) ^ mr)];
            acc[j] = __builtin_amdgcn_mfma_f32_16x16x32_bf16(a.v, b.v, acc[j], 0, 0, 0);
        }
    }

#pragma unroll
    for (int j = 0; j < 8; j++) {
        int n = j * 16 + mr;
        float cb = cb2[n];
#pragma unroll
        for (int r = 0; r < 4; r++) {
            int mrow = m0 + wave * 16 + q * 4 + r;
            if (mrow < N)
                uvb[(size_t)mrow * 128 + n] = f2bf(acc[j][r] + cb);
        }
    }
}

// ---------------- layer-2 finish: out = mean_agg(u) + v, fp32, unroll 8 ------
__global__ __launch_bounds__(256) void gather_out_bf(const unsigned short* __restrict__ uvb,
                                                     const unsigned* __restrict__ row_start,
                                                     const unsigned* __restrict__ csr_src,
                                                     float* __restrict__ out, int N) {
    int gid = blockIdx.x * 256 + threadIdx.x;
    int node = gid >> 3;
    if (node >= N) return;
    int f = (threadIdx.x & 7) * 8;
    unsigned s0 = row_start[node], s1 = row_start[node + 1];
    float acc[8];
#pragma unroll
    for (int i = 0; i < 8; i++) acc[i] = 0.f;
    unsigned i = s0;
    for (; i + 8 <= s1; i += 8) {
        unsigned i0 = csr_src[i + 0], i1 = csr_src[i + 1];
        unsigned i2 = csr_src[i + 2], i3 = csr_src[i + 3];
        unsigned i4 = csr_src[i + 4], i5 = csr_src[i + 5];
        unsigned i6 = csr_src[i + 6], i7 = csr_src[i + 7];
        uint4 d0 = *(const uint4*)(uvb + (size_t)i0 * 128 + f);
        uint4 d1 = *(const uint4*)(uvb + (size_t)i1 * 128 + f);
        uint4 d2 = *(const uint4*)(uvb + (size_t)i2 * 128 + f);
        uint4 d3 = *(const uint4*)(uvb + (size_t)i3 * 128 + f);
        uint4 d4 = *(const uint4*)(uvb + (size_t)i4 * 128 + f);
        uint4 d5 = *(const uint4*)(uvb + (size_t)i5 * 128 + f);
        uint4 d6 = *(const uint4*)(uvb + (size_t)i6 * 128 + f);
        uint4 d7 = *(const uint4*)(uvb + (size_t)i7 * 128 + f);
        acc8(acc, d0); acc8(acc, d1); acc8(acc, d2); acc8(acc, d3);
        acc8(acc, d4); acc8(acc, d5); acc8(acc, d6); acc8(acc, d7);
    }
    if (i + 4 <= s1) {
        unsigned i0 = csr_src[i + 0], i1 = csr_src[i + 1];
        unsigned i2 = csr_src[i + 2], i3 = csr_src[i + 3];
        uint4 d0 = *(const uint4*)(uvb + (size_t)i0 * 128 + f);
        uint4 d1 = *(const uint4*)(uvb + (size_t)i1 * 128 + f);
        uint4 d2 = *(const uint4*)(uvb + (size_t)i2 * 128 + f);
        uint4 d3 = *(const uint4*)(uvb + (size_t)i3 * 128 + f);
        acc8(acc, d0); acc8(acc, d1); acc8(acc, d2); acc8(acc, d3);
        i += 4;
    }
    if (i + 2 <= s1) {
        unsigned i0 = csr_src[i + 0], i1 = csr_src[i + 1];
        uint4 d0 = *(const uint4*)(uvb + (size_t)i0 * 128 + f);
        uint4 d1 = *(const uint4*)(uvb + (size_t)i1 * 128 + f);
        acc8(acc, d0); acc8(acc, d1);
        i += 2;
    }
    if (i < s1) {
        unsigned i0 = csr_src[i];
        uint4 d0 = *(const uint4*)(uvb + (size_t)i0 * 128 + f);
        acc8(acc, d0);
    }
    float inv = (s1 > s0) ? 1.0f / (float)(s1 - s0) : 0.f;
    uint4 dv = *(const uint4*)(uvb + (size_t)node * 128 + 64 + f);
    float vv[8];
    unpack2(dv.x, vv[0], vv[1]);
    unpack2(dv.y, vv[2], vv[3]);
    unpack2(dv.z, vv[4], vv[5]);
    unpack2(dv.w, vv[6], vv[7]);
    float4 o0 = make_float4(acc[0] * inv + vv[0], acc[1] * inv + vv[1],
                            acc[2] * inv + vv[2], acc[3] * inv + vv[3]);
    float4 o1 = make_float4(acc[4] * inv + vv[4], acc[5] * inv + vv[5],
                            acc[6] * inv + vv[6], acc[7] * inv + vv[7]);
    *(float4*)(out + (size_t)node * 64 + f) = o0;
    *(float4*)(out + (size_t)node * 64 + f + 4) = o1;
}

extern "C" void kernel_launch(void* const* d_in, const int* in_sizes, int n_in,
                              void* d_out, int out_size, void* d_ws, size_t ws_size,
                              hipStream_t stream) {
    const float* x     = (const float*)d_in[0];
    const int*   edge  = (const int*)d_in[1];
    const float* W1l   = (const float*)d_in[2];
    const float* b1    = (const float*)d_in[3];
    const float* W1r   = (const float*)d_in[4];
    const float* gamma = (const float*)d_in[5];
    const float* beta  = (const float*)d_in[6];
    const float* mean  = (const float*)d_in[7];
    const float* var   = (const float*)d_in[8];
    const float* W2l   = (const float*)d_in[9];
    const float* b2    = (const float*)d_in[10];
    const float* W2r   = (const float*)d_in[11];

    const int N = in_sizes[0] / FEAT;
    const int E = in_sizes[1] / 2;
    const int* srcI = edge;
    const int* dstI = edge + E;

    const int NB  = (N + BKT_NODES - 1) >> BKT_SHIFT;  // coarse buckets (196)
    const int M   = NB * P_CNT;                        // hist entries (200704)
    const int per = (E + P_CNT - 1) / P_CNT;           // edges per chunk block

    unsigned short* uvb  = (unsigned short*)d_ws;      // N*128
    unsigned short* aggb = uvb + (size_t)N * 128;      // N*128
    unsigned short* xb   = aggb + (size_t)N * 128;     // N*128
    unsigned short* Wb1  = xb + (size_t)N * 128;       // 128*256
    unsigned short* Wb2  = Wb1 + 256 * 128;            // 128*128
    float* bnsc = (float*)(Wb2 + 128 * 128);           // 128
    float* bnsh = bnsc + 128;                          // 128
    float* cb2  = bnsh + 128;                          // 128
    unsigned* histT     = (unsigned*)(cb2 + 128);      // M+1
    unsigned* hexcl     = histT + (M + 1);             // M+1
    unsigned* partials  = hexcl + (M + 1);             // 1024
    unsigned* row_start = partials + 1024;             // N+1
    unsigned* buck      = row_start + (N + 1);         // E (packed src|dstlow)
    unsigned* csr_src   = buck + E;                    // E

    float* outp = (float*)d_out;

    // front: LDS-hist count | convert | prep, one dispatch, no memset needed
    const int total8 = N * FEAT / 8;
    const int XB = (total8 + 255) / 256;
    const int PB = (128 * 256 + 255) / 256;            // weight-prep blocks
    front2<<<P_CNT + XB + PB, 256, 0, stream>>>(
        dstI, E, per, NB, histT, x, xb, XB,
        W1l, W1r, W2l, W2r, b1, gamma, beta, mean, var, b2,
        Wb1, Wb2, bnsc, bnsh, cb2);

    scan_block_c<<<M / 256, 256, 0, stream>>>(histT, hexcl, partials, M);
    scan_finish<<<M / 256, 256, 0, stream>>>(hexcl, partials, M, E);
    scatter_bucket<<<P_CNT, 256, 0, stream>>>(srcI, dstI, E, per, NB, hexcl, buck);
    bucket_csr<<<NB, BKT_NODES, 0, stream>>>(buck, hexcl, row_start, csr_src, N, E);

    // gather_mean: 128B-half XCD split; 32 nodes/block, 2 halves
    {
        const int NBLK = (N + 31) / 32;                 // node-blocks per half
        const int G = 8 * ((2 * NBLK + 7) / 8);         // both halves, xcd-aligned
        gather_mean_bf<<<G, 256, 0, stream>>>(xb, row_start, csr_src, aggb, N, NBLK);
    }
    sage_dense<<<(N + 127) / 128, 512, 0, stream>>>(aggb, xb, Wb1, Wb2, bnsc, bnsh, cb2, uvb, N);
    gather_out_bf<<<(N * 8 + 255) / 256, 256, 0, stream>>>(uvb, row_start, csr_src, outp, N);
}